// Round 10
// baseline (279.789 us; speedup 1.0000x reference)
//
#include <hip/hip_runtime.h>
#include <hip/hip_bf16.h>
#include <math.h>

// R17: kernel-count reduction (6 -> 4) targeting the ~150us hidden below the
// top-5 cutoff. mconv nulls (R10/R14/R15/R16 all ~45.4) say its structure is
// at its floor; attack elsewhere.
//  (a) k_attn = qk+pv fused. qk block (64 m, h, b) produces exactly the abits
//      slice pv block (same coords) consumes -> bits go through a double-
//      buffered 4KB LDS array with byte-layout IDENTICAL to the old global
//      abq (u64[m][quad] of wq u16s) -> pv's Qa/Qb reads bit-identical.
//      One barrier per t (ab double-buffered; WAR chain proven in comments).
//      Saves 6.3MB HBM round-trip + 1 launch + allows qk/pv overlap.
//      pv re-split over 4 waves as (dt=wv>>1, mg=wv&1), 2 mi each; LIF state
//      ownership constant across t. ay loads rolled per-s (L1-hot) for VGPR.
//  (b) k_pre = wsplit+lif merged by block range (data-independent bodies).
//  mconv (R16 triple-buffer) and mproj (R13 async) unchanged.

typedef __attribute__((ext_vector_type(8))) short short8;
typedef __attribute__((ext_vector_type(4))) float f32x4;

#define T_ 4
#define B_ 4
#define C_ 384
#define HW 1024
#define NH_ 12
#define Np_ 256
#define EPS_ 1e-5f

static __device__ __forceinline__ unsigned short f2bf(float f) {
    __hip_bfloat16 h = __float2bfloat16(f);
    return *reinterpret_cast<unsigned short*>(&h);
}
static __device__ __forceinline__ float bf2f(unsigned short u) {
    __hip_bfloat16 h = *reinterpret_cast<__hip_bfloat16*>(&u);
    return __bfloat162float(h);
}
static __device__ __forceinline__ void split3(float w, unsigned short& u0,
                                              unsigned short& u1, unsigned short& u2) {
    u0 = f2bf(w);  float f0 = bf2f(u0);
    float r1 = w - f0;
    u1 = f2bf(r1); float f1 = bf2f(u1);
    u2 = f2bf(r1 - f1);
}

// ---------------- K_pre: wsplit (blocks 0..5183) + lif_im2col (blocks 5184..6719) ----
__global__ __launch_bounds__(256) void k_pre(const float* __restrict__ Wc,
                                             const float* __restrict__ Wp,
                                             const float* __restrict__ x,
                                             unsigned short* __restrict__ Wc3,
                                             unsigned short* __restrict__ Wp3,
                                             unsigned short* __restrict__ Bc,
                                             unsigned short* __restrict__ xsb) {
    if (blockIdx.x < 5184) {
        const int NC = 768 * 1536;
        const int NP = 384 * 384;
        int i = blockIdx.x * 256 + threadIdx.x;
        float w; unsigned short* dst; int idx, plane;
        if (i < NC) { w = Wc[i]; dst = Wc3; idx = i; plane = NC; }
        else {
            int j = i - NC;
            if (j >= NP) return;
            w = Wp[j]; dst = Wp3; idx = j; plane = NP;
        }
        unsigned short u0, u1, u2;
        split3(w, u0, u1, u2);
        dst[idx] = u0; dst[plane + idx] = u1; dst[2 * plane + idx] = u2;
    } else {
        int gt = (blockIdx.x - 5184) * 256 + threadIdx.x;
        int pw = gt & 15, ph = (gt >> 4) & 15;
        int v = gt >> 8;
        int c = v % 384, b = v / 384;
        float v00 = 0.f, v01 = 0.f, v10 = 0.f, v11 = 0.f;
        const size_t xrow = ((size_t)b * C_ + c) * HW + (size_t)(2 * ph) * 32 + 2 * pw;
#pragma unroll
        for (int t = 0; t < T_; ++t) {
            const float* px = x + (size_t)t * (B_ * C_ * HW) + xrow;
            float2 r0 = *(const float2*)px;
            float2 r1 = *(const float2*)(px + 32);
            v00 += (r0.x - v00) * 0.5f;
            v01 += (r0.y - v01) * 0.5f;
            v10 += (r1.x - v10) * 0.5f;
            v11 += (r1.y - v11) * 0.5f;
            ushort4 s;
            s.x = (v00 >= 1.f) ? 0x3F80 : 0; if (v00 >= 1.f) v00 = 0.f;
            s.y = (v01 >= 1.f) ? 0x3F80 : 0; if (v01 >= 1.f) v01 = 0.f;
            s.z = (v10 >= 1.f) ? 0x3F80 : 0; if (v10 >= 1.f) v10 = 0.f;
            s.w = (v11 >= 1.f) ? 0x3F80 : 0; if (v11 >= 1.f) v11 = 0.f;
            int tb = t * B_ + b;
            int n = tb * 256 + ph * 16 + pw;
            *(ushort4*)(Bc + (size_t)n * 1536 + 4 * c) = s;
            size_t xo = ((size_t)tb * C_ + c) * HW + (size_t)(2 * ph) * 32 + 2 * pw;
            ushort2 w0 = {s.x, s.y}, w1 = {s.z, s.w};
            *(ushort2*)(xsb + xo) = w0;
            *(ushort2*)(xsb + xo + 32) = w1;
        }
    }
}

// ---------------- K2: conv GEMM via MFMA (R16 triple-buffer, proven 45.4us) ----------
#define GL16(GP, LP) __builtin_amdgcn_global_load_lds(                        \
    (const __attribute__((address_space(1))) void*)(GP),                      \
    (__attribute__((address_space(3))) void*)(LP), 16, 0, 0)

static __device__ __forceinline__ void stage_conv(const unsigned short* __restrict__ Wc3,
                                                  const unsigned short* __restrict__ Bc,
                                                  short* smb, int mb, int nb, int k0,
                                                  int wid, int rloc, int cswz) {
    if (wid == 0) {
#pragma unroll
        for (int s = 0; s < 3; ++s)
#pragma unroll
            for (int u = 0; u < 2; ++u)
                GL16(Wc3 + ((size_t)(s * 768 + mb * 32 + u * 16 + rloc)) * 1536 + k0 + cswz * 8,
                     smb + s * 1024 + u * 512);
        GL16(Bc + ((size_t)(nb * 128 + rloc)) * 1536 + k0 + cswz * 8, smb + 3072);
    } else {
#pragma unroll
        for (int v = 1; v < 8; ++v)
            GL16(Bc + ((size_t)(nb * 128 + v * 16 + rloc)) * 1536 + k0 + cswz * 8,
                 smb + 3072 + v * 512);
    }
}

__global__ __launch_bounds__(128) void k_mconv(const unsigned short* __restrict__ Bc,
                                               const unsigned short* __restrict__ Wc3,
                                               const float* __restrict__ g1,
                                               const float* __restrict__ b1,
                                               const float* __restrict__ frx,
                                               const float* __restrict__ fra,
                                               unsigned short* __restrict__ y1s,
                                               unsigned short* __restrict__ y2s) {
    __shared__ short sm[3][7168];
    const int nb = blockIdx.x, mb = blockIdx.y;
    const int tid = threadIdx.x;
    const int lane = tid & 63, wid = tid >> 6;
    const int quad = lane >> 4, lr = lane & 15;
    const int rloc = lane >> 2;
    const int cswz = (lane & 3) ^ ((lane >> 3) & 3);
    const int slot = quad ^ ((lr >> 1) & 3);
    const int wn = wid;

    f32x4 acc[2][4];
#pragma unroll
    for (int im = 0; im < 2; ++im)
#pragma unroll
        for (int in = 0; in < 4; ++in)
            acc[im][in] = (f32x4){0.f, 0.f, 0.f, 0.f};

    stage_conv(Wc3, Bc, sm[0], mb, nb, 0, wid, rloc, cswz);
    stage_conv(Wc3, Bc, sm[1], mb, nb, 32, wid, rloc, cswz);

#pragma unroll 3
    for (int kt = 0; kt < 48; ++kt) {
        if (kt < 47) { asm volatile("s_waitcnt vmcnt(7)" ::: "memory"); }
        else         { asm volatile("s_waitcnt vmcnt(0)" ::: "memory"); }
        asm volatile("" ::: "memory");
        __builtin_amdgcn_s_barrier();
        __builtin_amdgcn_sched_barrier(0);

        if (kt <= 45)
            stage_conv(Wc3, Bc, sm[(kt + 2) % 3], mb, nb, (kt + 2) * 32, wid, rloc, cswz);

        const short* smb = sm[kt % 3];
        short8 af[3][2], bf[4];
#pragma unroll
        for (int s = 0; s < 3; ++s)
#pragma unroll
            for (int im = 0; im < 2; ++im)
                af[s][im] = *(const short8*)&smb[s * 1024 + (im * 16 + lr) * 32 + slot * 8];
#pragma unroll
        for (int in = 0; in < 4; ++in)
            bf[in] = *(const short8*)&smb[3072 + (wn * 64 + in * 16 + lr) * 32 + slot * 8];

#pragma unroll
        for (int s = 0; s < 3; ++s)
#pragma unroll
            for (int im = 0; im < 2; ++im)
#pragma unroll
                for (int in = 0; in < 4; ++in)
                    acc[im][in] = __builtin_amdgcn_mfma_f32_16x16x32_bf16(af[s][im], bf[in], acc[im][in], 0, 0, 0);
    }

    const float rs = 1.0f / sqrtf(1.0f + EPS_);
    const int h = mb >> 1, half = mb & 1;
    const float scl = (half == 0) ? (1.0f / sqrtf(frx[h] * 32.0f))
                                  : (1.0f / sqrtf(fra[h] * 256.0f));
    unsigned short* dst = (half == 0) ? y1s : y2s;
#pragma unroll
    for (int im = 0; im < 2; ++im) {
#pragma unroll
        for (int in = 0; in < 4; ++in) {
            int n_g = nb * 128 + wn * 64 + in * 16 + lr;
            int tb = n_g >> 8, pn = n_g & 255;
            size_t base = (size_t)(tb * NH_ + h) * 3 * 8192;
            ushort4 o0, o1, o2;
#pragma unroll
            for (int r = 0; r < 4; ++r) {
                int oc = mb * 32 + im * 16 + quad * 4 + r;
                float val = (acc[im][in][r] * (g1[oc] * rs) + b1[oc]) * scl;
                unsigned short u0, u1, u2;
                split3(val, u0, u1, u2);
                ((unsigned short*)&o0)[r] = u0;
                ((unsigned short*)&o1)[r] = u1;
                ((unsigned short*)&o2)[r] = u2;
            }
            int dd = im * 16 + quad * 4;
            if (half == 0) {
                *(ushort4*)&dst[base + 0 * 8192 + (size_t)pn * 32 + dd] = o0;
                *(ushort4*)&dst[base + 1 * 8192 + (size_t)pn * 32 + dd] = o1;
                *(ushort4*)&dst[base + 2 * 8192 + (size_t)pn * 32 + dd] = o2;
            } else {
#pragma unroll
                for (int r = 0; r < 4; ++r) {
                    dst[base + 0 * 8192 + (size_t)(dd + r) * 256 + pn] = ((unsigned short*)&o0)[r];
                    dst[base + 1 * 8192 + (size_t)(dd + r) * 256 + pn] = ((unsigned short*)&o1)[r];
                    dst[base + 2 * 8192 + (size_t)(dd + r) * 256 + pn] = ((unsigned short*)&o2)[r];
                }
            }
        }
    }
}

// ---------------- K3: fused ein1+attnLIF+ein2+outLIF ----------------
// Block = (64 m-cols, h, b), 256 thr / 4 waves. Per t:
//   qk phase (wave role wq=wv): 12 MFMA per mi, LIF vat, bits -> ab[t&1] LDS
//     (byte-layout == old global abq: u64[m][quad] of wq u16 subwords).
//   barrier (one per t; ab double-buffered. WAR: qk(t+2) overwrites ab[t&1]
//     only after barrier(t+1), which all waves reach after pv(t) in program
//     order -> no race).
//   pv phase (wave role dt=wv>>1, mg=wv&1; 2 mi each): Qa/Qb from LDS,
//     bs build, 24 MFMA per mi (s outer, kt inner -- order identical to old
//     pv), LIF vo, store obt. ay loads rolled per-s (L1-hot) for VGPR.
__global__ __launch_bounds__(256) void k_attn(const unsigned short* __restrict__ xsb,
                                              const unsigned short* __restrict__ y1s,
                                              const unsigned short* __restrict__ y2s,
                                              unsigned short* __restrict__ obt) {
    __shared__ unsigned short xb[4][64][40];      // 20,480 B
    __shared__ unsigned long long ab[2][64][4];   //  4,096 B
    const int h = blockIdx.y, b = blockIdx.z;
    const int tid = threadIdx.x;
    const int lane = tid & 63, wv = tid >> 6;
    const int quad = lane >> 4, lr = lane & 15;
    const int m0 = blockIdx.x * 64;
    const int wq = wv;                            // qk role
    const int dt = wv >> 1, mg = wv & 1;          // pv role
    const int obase = (quad & 2) << 1;            // 0 or 4

    // stage xb with 16B-chunk XOR write swizzle (R13, kills 16-way conflict)
#pragma unroll
    for (int i = 0; i < 8; ++i) {
        int e = tid + i * 256;
        int j4 = e & 15, d = (e >> 4) & 31, t = e >> 9;
        ushort4 v = *(const ushort4*)(xsb + ((size_t)((t * B_ + b) * C_) + h * 32 + d) * HW + m0 + j4 * 4);
        int key = (j4 ^ (j4 >> 2)) & 3;
        int cc = ((((d >> 3) ^ key) << 3) | (d & 7));
        xb[t][j4 * 4 + 0][cc] = v.x;
        xb[t][j4 * 4 + 1][cc] = v.y;
        xb[t][j4 * 4 + 2][cc] = v.z;
        xb[t][j4 * 4 + 3][cc] = v.w;
    }
    __syncthreads();

    float vat[4][4][4];   // qk LIF state [mi][itl][r]
#pragma unroll
    for (int mi = 0; mi < 4; ++mi)
#pragma unroll
        for (int itl = 0; itl < 4; ++itl)
#pragma unroll
            for (int r = 0; r < 4; ++r) vat[mi][itl][r] = 0.f;
    float vo[2][4];       // pv LIF state [mi][r]
#pragma unroll
    for (int mi = 0; mi < 2; ++mi)
#pragma unroll
        for (int r = 0; r < 4; ++r) vo[mi][r] = 0.f;

    for (int t = 0; t < T_; ++t) {
        const int tb = t * B_ + b;
        const size_t slab = (size_t)(tb * NH_ + h) * 3 * 8192;

        // ---------- qk phase ----------
        short8 af[3][4];
        const unsigned short* y1p = y1s + slab + (size_t)(wq * 64 + lr) * 32 + quad * 8;
#pragma unroll
        for (int s = 0; s < 3; ++s)
#pragma unroll
            for (int itl = 0; itl < 4; ++itl)
                af[s][itl] = *(const short8*)(y1p + s * 8192 + itl * 512);

#pragma unroll
        for (int mi = 0; mi < 4; ++mi) {
            int keyr = ((lr >> 2) ^ mi) & 3;
            short8 bx = *(const short8*)&xb[t][mi * 16 + lr][(quad ^ keyr) * 8];
            f32x4 acc[4];
#pragma unroll
            for (int itl = 0; itl < 4; ++itl) acc[itl] = (f32x4){0.f, 0.f, 0.f, 0.f};
#pragma unroll
            for (int s = 0; s < 3; ++s)
#pragma unroll
                for (int itl = 0; itl < 4; ++itl)
                    acc[itl] = __builtin_amdgcn_mfma_f32_16x16x32_bf16(af[s][itl], bx, acc[itl], 0, 0, 0);

            unsigned int q = 0;
#pragma unroll
            for (int itl = 0; itl < 4; ++itl)
#pragma unroll
                for (int r = 0; r < 4; ++r) {
                    float v = vat[mi][itl][r];
                    v += (acc[itl][r] - v) * 0.5f;
                    bool s = (v >= 1.0f);
                    vat[mi][itl][r] = s ? 0.f : v;
                    q |= (s ? 1u : 0u) << (itl * 4 + r);
                }
            ((unsigned short*)&ab[t & 1][mi * 16 + lr][quad])[wq] = (unsigned short)q;
        }
        __syncthreads();   // bits of t visible; also orders pv(t-1) before qk(t+1) WAR

        // ---------- pv phase ----------
        const unsigned short* y2p = y2s + slab + (size_t)(dt * 16 + lr) * 256 + quad * 8;
#pragma unroll
        for (int mi = 0; mi < 2; ++mi) {
            const int mloc = mg * 32 + mi * 16 + lr;
            unsigned long long Qa = ab[t & 1][mloc][(quad & 1) * 2];
            unsigned long long Qb = ab[t & 1][mloc][(quad & 1) * 2 + 1];

            short8 bs[8];
#pragma unroll
            for (int kt = 0; kt < 8; ++kt) {
                int o = kt * 8 + obase;
                unsigned int a4 = (unsigned int)(Qa >> o) & 15u;
                unsigned int b4 = (unsigned int)(Qb >> o) & 15u;
                union { short8 v; unsigned int w[4]; } u;
                u.w[0] = ((a4 & 1u) ? 0x3F80u : 0u) | ((a4 & 2u) ? 0x3F800000u : 0u);
                u.w[1] = ((a4 & 4u) ? 0x3F80u : 0u) | ((a4 & 8u) ? 0x3F800000u : 0u);
                u.w[2] = ((b4 & 1u) ? 0x3F80u : 0u) | ((b4 & 2u) ? 0x3F800000u : 0u);
                u.w[3] = ((b4 & 4u) ? 0x3F80u : 0u) | ((b4 & 8u) ? 0x3F800000u : 0u);
                bs[kt] = u.v;
            }

            f32x4 acc2 = (f32x4){0.f, 0.f, 0.f, 0.f};
#pragma unroll
            for (int s = 0; s < 3; ++s) {
                short8 ays[8];
#pragma unroll
                for (int kt = 0; kt < 8; ++kt)
                    ays[kt] = *(const short8*)(y2p + s * 8192 + kt * 32);
#pragma unroll
                for (int kt = 0; kt < 8; ++kt)
                    acc2 = __builtin_amdgcn_mfma_f32_16x16x32_bf16(ays[kt], bs[kt], acc2, 0, 0, 0);
            }

            ushort4 ob;
#pragma unroll
            for (int r = 0; r < 4; ++r) {
                float v = vo[mi][r];
                v += (acc2[r] - v) * 0.5f;
                bool s = (v >= 1.0f);
                ((unsigned short*)&ob)[r] = s ? 0x3F80 : 0;
                vo[mi][r] = s ? 0.f : v;
            }
            const int m = m0 + mloc;
            *(ushort4*)(obt + ((size_t)tb * HW + m) * C_ + h * 32 + dt * 16 + quad * 4) = ob;
        }
    }
}

// ---------------- K4: proj GEMM via MFMA + BN2 + residual (R13 async) ----------------
static __device__ __forceinline__ void stage_proj(const unsigned short* __restrict__ Wp3,
                                                  const unsigned short* __restrict__ obt,
                                                  short* smb, int mb, int nb, int k0,
                                                  int wid, int rloc, int cswz) {
    if (wid < 3) {
#pragma unroll
        for (int u = 0; u < 4; ++u)
            GL16(Wp3 + ((size_t)(wid * 384 + mb * 64 + u * 16 + rloc)) * 384 + k0 + cswz * 8,
                 smb + wid * 2048 + u * 512);
        GL16(obt + ((size_t)(nb * 128 + wid * 16 + rloc)) * 384 + k0 + cswz * 8,
             smb + 6144 + wid * 512);
    } else {
#pragma unroll
        for (int v = 3; v < 8; ++v)
            GL16(obt + ((size_t)(nb * 128 + v * 16 + rloc)) * 384 + k0 + cswz * 8,
                 smb + 6144 + v * 512);
    }
}

__global__ __launch_bounds__(256) void k_mproj(const unsigned short* __restrict__ obt,
                                               const unsigned short* __restrict__ Wp3,
                                               const float* __restrict__ g2,
                                               const float* __restrict__ b2,
                                               const float* __restrict__ x,
                                               float* __restrict__ out) {
    __shared__ short sm[2][10240];
    const int nb = blockIdx.x, mb = blockIdx.y;
    const int tid = threadIdx.x;
    const int lane = tid & 63, wave = tid >> 6;
    const int wm = wave >> 1, wn = wave & 1;
    const int quad = lane >> 4, lr = lane & 15;
    const int rloc = lane >> 2;
    const int cswz = (lane & 3) ^ ((lane >> 3) & 3);
    const int slot = quad ^ ((lr >> 1) & 3);

    f32x4 acc[2][4];
#pragma unroll
    for (int im = 0; im < 2; ++im)
#pragma unroll
        for (int in = 0; in < 4; ++in)
            acc[im][in] = (f32x4){0.f, 0.f, 0.f, 0.f};

    stage_proj(Wp3, obt, sm[0], mb, nb, 0, wave, rloc, cswz);

    for (int kt = 0; kt < 12; ++kt) {
        const int b = kt & 1;
        if (kt < 11) {
            stage_proj(Wp3, obt, sm[b ^ 1], mb, nb, (kt + 1) * 32, wave, rloc, cswz);
            asm volatile("s_waitcnt vmcnt(5)" ::: "memory");
        } else {
            asm volatile("s_waitcnt vmcnt(0)" ::: "memory");
        }
        __builtin_amdgcn_s_barrier();
        __builtin_amdgcn_sched_barrier(0);

        const short* smb = sm[b];
        short8 af[3][2], bf[4];
#pragma unroll
        for (int s = 0; s < 3; ++s)
#pragma unroll
            for (int im = 0; im < 2; ++im)
                af[s][im] = *(const short8*)&smb[s * 2048 + (wm * 32 + im * 16 + lr) * 32 + slot * 8];
#pragma unroll
        for (int in = 0; in < 4; ++in)
            bf[in] = *(const short8*)&smb[6144 + (wn * 64 + in * 16 + lr) * 32 + slot * 8];
        asm volatile("s_waitcnt lgkmcnt(0)" ::: "memory");
        __builtin_amdgcn_sched_barrier(0);
        __builtin_amdgcn_s_barrier();
        __builtin_amdgcn_sched_barrier(0);

#pragma unroll
        for (int s = 0; s < 3; ++s)
#pragma unroll
            for (int im = 0; im < 2; ++im)
#pragma unroll
                for (int in = 0; in < 4; ++in)
                    acc[im][in] = __builtin_amdgcn_mfma_f32_16x16x32_bf16(af[s][im], bf[in], acc[im][in], 0, 0, 0);
    }

    const float rs = 1.0f / sqrtf(1.0f + EPS_);
#pragma unroll
    for (int im = 0; im < 2; ++im) {
#pragma unroll
        for (int in = 0; in < 4; ++in) {
            int n_g = nb * 128 + wn * 64 + in * 16 + lr;
            int tb = n_g >> 10, hw = n_g & 1023;
#pragma unroll
            for (int r = 0; r < 4; ++r) {
                int o = mb * 64 + wm * 32 + im * 16 + quad * 4 + r;
                size_t idx = ((size_t)tb * C_ + o) * HW + hw;
                out[idx] = acc[im][in][r] * (g2[o] * rs) + b2[o] + x[idx];
            }
        }
    }
}

extern "C" void kernel_launch(void* const* d_in, const int* in_sizes, int n_in,
                              void* d_out, int out_size, void* d_ws, size_t ws_size,
                              hipStream_t stream) {
    const float* x      = (const float*)d_in[0];
    const float* Wconv  = (const float*)d_in[1];
    const float* gamma1 = (const float*)d_in[2];
    const float* beta1  = (const float*)d_in[3];
    const float* Wproj  = (const float*)d_in[4];
    const float* gamma2 = (const float*)d_in[5];
    const float* beta2  = (const float*)d_in[6];
    const float* frx    = (const float*)d_in[7];
    const float* fra    = (const float*)d_in[8];
    float* out = (float*)d_out;

    unsigned short* ws16 = (unsigned short*)d_ws;
    unsigned short* Bc  = ws16;                 // aliased by obt after k_mconv
    unsigned short* obt = ws16;
    unsigned short* Wc3 = ws16 + 6291456;
    unsigned short* Wp3 = ws16 + 9830400;
    unsigned short* xsb = ws16 + 10272768;
    unsigned short* y1s = ws16 + 16564224;
    unsigned short* y2s = ws16 + 21282816;

    k_pre<<<6720, 256, 0, stream>>>(Wconv, Wproj, x, Wc3, Wp3, Bc, xsb);
    k_mconv<<<dim3(32, 24), 128, 0, stream>>>(Bc, Wc3, gamma1, beta1, frx, fra, y1s, y2s);
    k_attn<<<dim3(16, 12, 4), 256, 0, stream>>>(xsb, y1s, y2s, obt);
    k_mproj<<<dim3(128, 6), 256, 0, stream>>>(obt, Wp3, gamma2, beta2, x, out);
}

// Round 11
// 245.993 us; speedup vs baseline: 1.1374x; 1.1374x over previous
//
#include <hip/hip_runtime.h>
#include <hip/hip_bf16.h>
#include <math.h>

// R18: revert R17's qk+pv fusion (k_attn 108us vs ~65-70 separate: per-t
// barrier serialized the phases, 1-blk/CU residency killed y2 L1 reuse,
// FETCH 44->80MB). Keep k_pre (wsplit+lif block-range merge, risk-free).
// Config = session best: k_pre + R16 triple-buffer mconv (45.4us proven) +
// R13 swizzled qk + R11 768-block pv + R13 async mproj.

typedef __attribute__((ext_vector_type(8))) short short8;
typedef __attribute__((ext_vector_type(4))) float f32x4;

#define T_ 4
#define B_ 4
#define C_ 384
#define HW 1024
#define NH_ 12
#define Np_ 256
#define EPS_ 1e-5f

static __device__ __forceinline__ unsigned short f2bf(float f) {
    __hip_bfloat16 h = __float2bfloat16(f);
    return *reinterpret_cast<unsigned short*>(&h);
}
static __device__ __forceinline__ float bf2f(unsigned short u) {
    __hip_bfloat16 h = *reinterpret_cast<__hip_bfloat16*>(&u);
    return __bfloat162float(h);
}
static __device__ __forceinline__ void split3(float w, unsigned short& u0,
                                              unsigned short& u1, unsigned short& u2) {
    u0 = f2bf(w);  float f0 = bf2f(u0);
    float r1 = w - f0;
    u1 = f2bf(r1); float f1 = bf2f(u1);
    u2 = f2bf(r1 - f1);
}

// ---------------- K_pre: wsplit (blocks 0..5183) + lif_im2col (blocks 5184..6719) ----
__global__ __launch_bounds__(256) void k_pre(const float* __restrict__ Wc,
                                             const float* __restrict__ Wp,
                                             const float* __restrict__ x,
                                             unsigned short* __restrict__ Wc3,
                                             unsigned short* __restrict__ Wp3,
                                             unsigned short* __restrict__ Bc,
                                             unsigned short* __restrict__ xsb) {
    if (blockIdx.x < 5184) {
        const int NC = 768 * 1536;
        const int NP = 384 * 384;
        int i = blockIdx.x * 256 + threadIdx.x;
        float w; unsigned short* dst; int idx, plane;
        if (i < NC) { w = Wc[i]; dst = Wc3; idx = i; plane = NC; }
        else {
            int j = i - NC;
            if (j >= NP) return;
            w = Wp[j]; dst = Wp3; idx = j; plane = NP;
        }
        unsigned short u0, u1, u2;
        split3(w, u0, u1, u2);
        dst[idx] = u0; dst[plane + idx] = u1; dst[2 * plane + idx] = u2;
    } else {
        int gt = (blockIdx.x - 5184) * 256 + threadIdx.x;
        int pw = gt & 15, ph = (gt >> 4) & 15;
        int v = gt >> 8;
        int c = v % 384, b = v / 384;
        float v00 = 0.f, v01 = 0.f, v10 = 0.f, v11 = 0.f;
        const size_t xrow = ((size_t)b * C_ + c) * HW + (size_t)(2 * ph) * 32 + 2 * pw;
#pragma unroll
        for (int t = 0; t < T_; ++t) {
            const float* px = x + (size_t)t * (B_ * C_ * HW) + xrow;
            float2 r0 = *(const float2*)px;
            float2 r1 = *(const float2*)(px + 32);
            v00 += (r0.x - v00) * 0.5f;
            v01 += (r0.y - v01) * 0.5f;
            v10 += (r1.x - v10) * 0.5f;
            v11 += (r1.y - v11) * 0.5f;
            ushort4 s;
            s.x = (v00 >= 1.f) ? 0x3F80 : 0; if (v00 >= 1.f) v00 = 0.f;
            s.y = (v01 >= 1.f) ? 0x3F80 : 0; if (v01 >= 1.f) v01 = 0.f;
            s.z = (v10 >= 1.f) ? 0x3F80 : 0; if (v10 >= 1.f) v10 = 0.f;
            s.w = (v11 >= 1.f) ? 0x3F80 : 0; if (v11 >= 1.f) v11 = 0.f;
            int tb = t * B_ + b;
            int n = tb * 256 + ph * 16 + pw;
            *(ushort4*)(Bc + (size_t)n * 1536 + 4 * c) = s;
            size_t xo = ((size_t)tb * C_ + c) * HW + (size_t)(2 * ph) * 32 + 2 * pw;
            ushort2 w0 = {s.x, s.y}, w1 = {s.z, s.w};
            *(ushort2*)(xsb + xo) = w0;
            *(ushort2*)(xsb + xo + 32) = w1;
        }
    }
}

// ---------------- K2: conv GEMM via MFMA (R16 triple-buffer, proven 45.4us) ----------
#define GL16(GP, LP) __builtin_amdgcn_global_load_lds(                        \
    (const __attribute__((address_space(1))) void*)(GP),                      \
    (__attribute__((address_space(3))) void*)(LP), 16, 0, 0)

static __device__ __forceinline__ void stage_conv(const unsigned short* __restrict__ Wc3,
                                                  const unsigned short* __restrict__ Bc,
                                                  short* smb, int mb, int nb, int k0,
                                                  int wid, int rloc, int cswz) {
    if (wid == 0) {
#pragma unroll
        for (int s = 0; s < 3; ++s)
#pragma unroll
            for (int u = 0; u < 2; ++u)
                GL16(Wc3 + ((size_t)(s * 768 + mb * 32 + u * 16 + rloc)) * 1536 + k0 + cswz * 8,
                     smb + s * 1024 + u * 512);
        GL16(Bc + ((size_t)(nb * 128 + rloc)) * 1536 + k0 + cswz * 8, smb + 3072);
    } else {
#pragma unroll
        for (int v = 1; v < 8; ++v)
            GL16(Bc + ((size_t)(nb * 128 + v * 16 + rloc)) * 1536 + k0 + cswz * 8,
                 smb + 3072 + v * 512);
    }
}

__global__ __launch_bounds__(128) void k_mconv(const unsigned short* __restrict__ Bc,
                                               const unsigned short* __restrict__ Wc3,
                                               const float* __restrict__ g1,
                                               const float* __restrict__ b1,
                                               const float* __restrict__ frx,
                                               const float* __restrict__ fra,
                                               unsigned short* __restrict__ y1s,
                                               unsigned short* __restrict__ y2s) {
    __shared__ short sm[3][7168];
    const int nb = blockIdx.x, mb = blockIdx.y;
    const int tid = threadIdx.x;
    const int lane = tid & 63, wid = tid >> 6;
    const int quad = lane >> 4, lr = lane & 15;
    const int rloc = lane >> 2;
    const int cswz = (lane & 3) ^ ((lane >> 3) & 3);
    const int slot = quad ^ ((lr >> 1) & 3);
    const int wn = wid;

    f32x4 acc[2][4];
#pragma unroll
    for (int im = 0; im < 2; ++im)
#pragma unroll
        for (int in = 0; in < 4; ++in)
            acc[im][in] = (f32x4){0.f, 0.f, 0.f, 0.f};

    stage_conv(Wc3, Bc, sm[0], mb, nb, 0, wid, rloc, cswz);
    stage_conv(Wc3, Bc, sm[1], mb, nb, 32, wid, rloc, cswz);

#pragma unroll 3
    for (int kt = 0; kt < 48; ++kt) {
        if (kt < 47) { asm volatile("s_waitcnt vmcnt(7)" ::: "memory"); }
        else         { asm volatile("s_waitcnt vmcnt(0)" ::: "memory"); }
        asm volatile("" ::: "memory");
        __builtin_amdgcn_s_barrier();
        __builtin_amdgcn_sched_barrier(0);

        if (kt <= 45)
            stage_conv(Wc3, Bc, sm[(kt + 2) % 3], mb, nb, (kt + 2) * 32, wid, rloc, cswz);

        const short* smb = sm[kt % 3];
        short8 af[3][2], bf[4];
#pragma unroll
        for (int s = 0; s < 3; ++s)
#pragma unroll
            for (int im = 0; im < 2; ++im)
                af[s][im] = *(const short8*)&smb[s * 1024 + (im * 16 + lr) * 32 + slot * 8];
#pragma unroll
        for (int in = 0; in < 4; ++in)
            bf[in] = *(const short8*)&smb[3072 + (wn * 64 + in * 16 + lr) * 32 + slot * 8];

#pragma unroll
        for (int s = 0; s < 3; ++s)
#pragma unroll
            for (int im = 0; im < 2; ++im)
#pragma unroll
                for (int in = 0; in < 4; ++in)
                    acc[im][in] = __builtin_amdgcn_mfma_f32_16x16x32_bf16(af[s][im], bf[in], acc[im][in], 0, 0, 0);
    }

    const float rs = 1.0f / sqrtf(1.0f + EPS_);
    const int h = mb >> 1, half = mb & 1;
    const float scl = (half == 0) ? (1.0f / sqrtf(frx[h] * 32.0f))
                                  : (1.0f / sqrtf(fra[h] * 256.0f));
    unsigned short* dst = (half == 0) ? y1s : y2s;
#pragma unroll
    for (int im = 0; im < 2; ++im) {
#pragma unroll
        for (int in = 0; in < 4; ++in) {
            int n_g = nb * 128 + wn * 64 + in * 16 + lr;
            int tb = n_g >> 8, pn = n_g & 255;
            size_t base = (size_t)(tb * NH_ + h) * 3 * 8192;
            ushort4 o0, o1, o2;
#pragma unroll
            for (int r = 0; r < 4; ++r) {
                int oc = mb * 32 + im * 16 + quad * 4 + r;
                float val = (acc[im][in][r] * (g1[oc] * rs) + b1[oc]) * scl;
                unsigned short u0, u1, u2;
                split3(val, u0, u1, u2);
                ((unsigned short*)&o0)[r] = u0;
                ((unsigned short*)&o1)[r] = u1;
                ((unsigned short*)&o2)[r] = u2;
            }
            int dd = im * 16 + quad * 4;
            if (half == 0) {
                *(ushort4*)&dst[base + 0 * 8192 + (size_t)pn * 32 + dd] = o0;
                *(ushort4*)&dst[base + 1 * 8192 + (size_t)pn * 32 + dd] = o1;
                *(ushort4*)&dst[base + 2 * 8192 + (size_t)pn * 32 + dd] = o2;
            } else {
#pragma unroll
                for (int r = 0; r < 4; ++r) {
                    dst[base + 0 * 8192 + (size_t)(dd + r) * 256 + pn] = ((unsigned short*)&o0)[r];
                    dst[base + 1 * 8192 + (size_t)(dd + r) * 256 + pn] = ((unsigned short*)&o1)[r];
                    dst[base + 2 * 8192 + (size_t)(dd + r) * 256 + pn] = ((unsigned short*)&o2)[r];
                }
            }
        }
    }
}

// ---------------- K3a: ein1 + attn-LIF -> packed spike bits ----------------
// xb 16B-chunk XOR swizzle kills the 16-way staging-write bank conflict.
__global__ __launch_bounds__(256, 2) void k_attn_qk(const unsigned short* __restrict__ xsb,
                                                    const unsigned short* __restrict__ y1s,
                                                    unsigned short* __restrict__ abq) {
    __shared__ unsigned short xb[4][64][40];   // [t][m][d] : 20,480 B
    const int h = blockIdx.y, b = blockIdx.z;
    const int tid = threadIdx.x;
    const int lane = tid & 63, wq = tid >> 6;
    const int quad = lane >> 4, lr = lane & 15;
    const int m0 = blockIdx.x * 64;

#pragma unroll
    for (int i = 0; i < 8; ++i) {
        int e = tid + i * 256;                 // 2048 ushort4 = 4t*64m*32d
        int j4 = e & 15, d = (e >> 4) & 31, t = e >> 9;
        ushort4 v = *(const ushort4*)(xsb + ((size_t)((t * B_ + b) * C_) + h * 32 + d) * HW + m0 + j4 * 4);
        int key = (j4 ^ (j4 >> 2)) & 3;
        int cc = ((((d >> 3) ^ key) << 3) | (d & 7));
        xb[t][j4 * 4 + 0][cc] = v.x;
        xb[t][j4 * 4 + 1][cc] = v.y;
        xb[t][j4 * 4 + 2][cc] = v.z;
        xb[t][j4 * 4 + 3][cc] = v.w;
    }
    __syncthreads();   // only barrier; t/m loops below are wave-autonomous

    float vat[4][4][4];   // [mi][itl][r] attn-LIF state
#pragma unroll
    for (int mi = 0; mi < 4; ++mi)
#pragma unroll
        for (int itl = 0; itl < 4; ++itl)
#pragma unroll
            for (int r = 0; r < 4; ++r) vat[mi][itl][r] = 0.f;

#pragma unroll
    for (int t = 0; t < T_; ++t) {
        const int tb = t * B_ + b;
        const size_t slab = (size_t)(tb * NH_ + h) * 3 * 8192;

        // m-invariant A-fragments: 12 loads, reused by all 4 m-tiles
        short8 af[3][4];
        const unsigned short* y1p = y1s + slab + (size_t)(wq * 64 + lr) * 32 + quad * 8;
#pragma unroll
        for (int s = 0; s < 3; ++s)
#pragma unroll
            for (int itl = 0; itl < 4; ++itl)
                af[s][itl] = *(const short8*)(y1p + s * 8192 + itl * 512);

#pragma unroll
        for (int mi = 0; mi < 4; ++mi) {
            int keyr = ((lr >> 2) ^ mi) & 3;
            short8 bx = *(const short8*)&xb[t][mi * 16 + lr][(quad ^ keyr) * 8];
            f32x4 acc[4];
#pragma unroll
            for (int itl = 0; itl < 4; ++itl) acc[itl] = (f32x4){0.f, 0.f, 0.f, 0.f};
#pragma unroll
            for (int s = 0; s < 3; ++s)
#pragma unroll
                for (int itl = 0; itl < 4; ++itl)
                    acc[itl] = __builtin_amdgcn_mfma_f32_16x16x32_bf16(af[s][itl], bx, acc[itl], 0, 0, 0);

            unsigned int q = 0;
#pragma unroll
            for (int itl = 0; itl < 4; ++itl)
#pragma unroll
                for (int r = 0; r < 4; ++r) {
                    float v = vat[mi][itl][r];
                    v += (acc[itl][r] - v) * 0.5f;
                    bool s = (v >= 1.0f);
                    vat[mi][itl][r] = s ? 0.f : v;
                    q |= (s ? 1u : 0u) << (itl * 4 + r);
                }
            int m = m0 + mi * 16 + lr;
            abq[(((size_t)(tb * NH_ + h) * 1024 + m) * 4 + quad) * 4 + wq] = (unsigned short)q;
        }
    }
}

// ---------------- K3b: ein2 + out-LIF (no LDS, no barriers) ----------------
__global__ __launch_bounds__(128) void k_attn_pv(const unsigned long long* __restrict__ abits,
                                                 const unsigned short* __restrict__ y2s,
                                                 unsigned short* __restrict__ obt) {
    const int h = blockIdx.y, b = blockIdx.z;
    const int tid = threadIdx.x;
    const int lane = tid & 63;
    const int quad = lane >> 4, lr = lane & 15;
    const int dt = tid >> 6;                     // wave id = d-half owner
    const int mbase = blockIdx.x * 64;
    const int obase = (quad & 2) << 1;   // 0 or 4

    float vo[4][4];
#pragma unroll
    for (int mi = 0; mi < 4; ++mi)
#pragma unroll
        for (int r = 0; r < 4; ++r) vo[mi][r] = 0.f;

#pragma unroll
    for (int t = 0; t < T_; ++t) {
        const int tb = t * B_ + b;
        const size_t slab = (size_t)(tb * NH_ + h) * 3 * 8192;

        // m-invariant A-fragments: 24 loads, reused by all 4 m-tiles
        short8 ay[3][8];
        const unsigned short* y2p = y2s + slab + (size_t)(dt * 16 + lr) * 256 + quad * 8;
#pragma unroll
        for (int s = 0; s < 3; ++s)
#pragma unroll
            for (int kt = 0; kt < 8; ++kt)
                ay[s][kt] = *(const short8*)(y2p + s * 8192 + kt * 32);

#pragma unroll
        for (int mi = 0; mi < 4; ++mi) {
            const int m = mbase + mi * 16 + lr;
            const unsigned long long* ap = abits + ((size_t)(tb * NH_ + h) * 1024 + m) * 4 + (quad & 1) * 2;
            unsigned long long Qa = ap[0];
            unsigned long long Qb = ap[1];

            short8 bs[8];
#pragma unroll
            for (int kt = 0; kt < 8; ++kt) {
                int o = kt * 8 + obase;
                unsigned int a4 = (unsigned int)(Qa >> o) & 15u;
                unsigned int b4 = (unsigned int)(Qb >> o) & 15u;
                union { short8 v; unsigned int w[4]; } u;
                u.w[0] = ((a4 & 1u) ? 0x3F80u : 0u) | ((a4 & 2u) ? 0x3F800000u : 0u);
                u.w[1] = ((a4 & 4u) ? 0x3F80u : 0u) | ((a4 & 8u) ? 0x3F800000u : 0u);
                u.w[2] = ((b4 & 1u) ? 0x3F80u : 0u) | ((b4 & 2u) ? 0x3F800000u : 0u);
                u.w[3] = ((b4 & 4u) ? 0x3F80u : 0u) | ((b4 & 8u) ? 0x3F800000u : 0u);
                bs[kt] = u.v;
            }

            f32x4 acc2 = (f32x4){0.f, 0.f, 0.f, 0.f};
#pragma unroll
            for (int s = 0; s < 3; ++s)
#pragma unroll
                for (int kt = 0; kt < 8; ++kt)
                    acc2 = __builtin_amdgcn_mfma_f32_16x16x32_bf16(ay[s][kt], bs[kt], acc2, 0, 0, 0);

            ushort4 ob;
#pragma unroll
            for (int r = 0; r < 4; ++r) {
                float v = vo[mi][r];
                v += (acc2[r] - v) * 0.5f;
                bool s = (v >= 1.0f);
                ((unsigned short*)&ob)[r] = s ? 0x3F80 : 0;
                vo[mi][r] = s ? 0.f : v;
            }
            *(ushort4*)(obt + ((size_t)tb * HW + m) * C_ + h * 32 + dt * 16 + quad * 4) = ob;
        }
    }
}

// ---------------- K4: proj GEMM via MFMA + BN2 + residual (R13 async) ----------------
static __device__ __forceinline__ void stage_proj(const unsigned short* __restrict__ Wp3,
                                                  const unsigned short* __restrict__ obt,
                                                  short* smb, int mb, int nb, int k0,
                                                  int wid, int rloc, int cswz) {
    if (wid < 3) {
#pragma unroll
        for (int u = 0; u < 4; ++u)
            GL16(Wp3 + ((size_t)(wid * 384 + mb * 64 + u * 16 + rloc)) * 384 + k0 + cswz * 8,
                 smb + wid * 2048 + u * 512);
        GL16(obt + ((size_t)(nb * 128 + wid * 16 + rloc)) * 384 + k0 + cswz * 8,
             smb + 6144 + wid * 512);
    } else {
#pragma unroll
        for (int v = 3; v < 8; ++v)
            GL16(obt + ((size_t)(nb * 128 + v * 16 + rloc)) * 384 + k0 + cswz * 8,
                 smb + 6144 + v * 512);
    }
}

__global__ __launch_bounds__(256) void k_mproj(const unsigned short* __restrict__ obt,
                                               const unsigned short* __restrict__ Wp3,
                                               const float* __restrict__ g2,
                                               const float* __restrict__ b2,
                                               const float* __restrict__ x,
                                               float* __restrict__ out) {
    __shared__ short sm[2][10240];
    const int nb = blockIdx.x, mb = blockIdx.y;
    const int tid = threadIdx.x;
    const int lane = tid & 63, wave = tid >> 6;
    const int wm = wave >> 1, wn = wave & 1;
    const int quad = lane >> 4, lr = lane & 15;
    const int rloc = lane >> 2;
    const int cswz = (lane & 3) ^ ((lane >> 3) & 3);
    const int slot = quad ^ ((lr >> 1) & 3);

    f32x4 acc[2][4];
#pragma unroll
    for (int im = 0; im < 2; ++im)
#pragma unroll
        for (int in = 0; in < 4; ++in)
            acc[im][in] = (f32x4){0.f, 0.f, 0.f, 0.f};

    stage_proj(Wp3, obt, sm[0], mb, nb, 0, wave, rloc, cswz);

    for (int kt = 0; kt < 12; ++kt) {
        const int b = kt & 1;
        if (kt < 11) {
            stage_proj(Wp3, obt, sm[b ^ 1], mb, nb, (kt + 1) * 32, wave, rloc, cswz);
            asm volatile("s_waitcnt vmcnt(5)" ::: "memory");
        } else {
            asm volatile("s_waitcnt vmcnt(0)" ::: "memory");
        }
        __builtin_amdgcn_s_barrier();
        __builtin_amdgcn_sched_barrier(0);

        const short* smb = sm[b];
        short8 af[3][2], bf[4];
#pragma unroll
        for (int s = 0; s < 3; ++s)
#pragma unroll
            for (int im = 0; im < 2; ++im)
                af[s][im] = *(const short8*)&smb[s * 2048 + (wm * 32 + im * 16 + lr) * 32 + slot * 8];
#pragma unroll
        for (int in = 0; in < 4; ++in)
            bf[in] = *(const short8*)&smb[6144 + (wn * 64 + in * 16 + lr) * 32 + slot * 8];
        asm volatile("s_waitcnt lgkmcnt(0)" ::: "memory");
        __builtin_amdgcn_sched_barrier(0);
        __builtin_amdgcn_s_barrier();
        __builtin_amdgcn_sched_barrier(0);

#pragma unroll
        for (int s = 0; s < 3; ++s)
#pragma unroll
            for (int im = 0; im < 2; ++im)
#pragma unroll
                for (int in = 0; in < 4; ++in)
                    acc[im][in] = __builtin_amdgcn_mfma_f32_16x16x32_bf16(af[s][im], bf[in], acc[im][in], 0, 0, 0);
    }

    const float rs = 1.0f / sqrtf(1.0f + EPS_);
#pragma unroll
    for (int im = 0; im < 2; ++im) {
#pragma unroll
        for (int in = 0; in < 4; ++in) {
            int n_g = nb * 128 + wn * 64 + in * 16 + lr;
            int tb = n_g >> 10, hw = n_g & 1023;
#pragma unroll
            for (int r = 0; r < 4; ++r) {
                int o = mb * 64 + wm * 32 + im * 16 + quad * 4 + r;
                size_t idx = ((size_t)tb * C_ + o) * HW + hw;
                out[idx] = acc[im][in][r] * (g2[o] * rs) + b2[o] + x[idx];
            }
        }
    }
}

extern "C" void kernel_launch(void* const* d_in, const int* in_sizes, int n_in,
                              void* d_out, int out_size, void* d_ws, size_t ws_size,
                              hipStream_t stream) {
    const float* x      = (const float*)d_in[0];
    const float* Wconv  = (const float*)d_in[1];
    const float* gamma1 = (const float*)d_in[2];
    const float* beta1  = (const float*)d_in[3];
    const float* Wproj  = (const float*)d_in[4];
    const float* gamma2 = (const float*)d_in[5];
    const float* beta2  = (const float*)d_in[6];
    const float* frx    = (const float*)d_in[7];
    const float* fra    = (const float*)d_in[8];
    float* out = (float*)d_out;

    unsigned short* ws16 = (unsigned short*)d_ws;
    unsigned short* Bc  = ws16;                 // aliased by obt after k_mconv
    unsigned short* obt = ws16;
    unsigned short* Wc3 = ws16 + 6291456;
    unsigned short* Wp3 = ws16 + 9830400;
    unsigned short* xsb = ws16 + 10272768;
    unsigned short* y1s = ws16 + 16564224;
    unsigned short* y2s = ws16 + 21282816;
    unsigned long long* abits = (unsigned long long*)(ws16 + 26001408);  // 6.3 MB

    k_pre<<<6720, 256, 0, stream>>>(Wconv, Wproj, x, Wc3, Wp3, Bc, xsb);
    k_mconv<<<dim3(32, 24), 128, 0, stream>>>(Bc, Wc3, gamma1, beta1, frx, fra, y1s, y2s);
    k_attn_qk<<<dim3(16, 12, 4), 256, 0, stream>>>(xsb, y1s, (unsigned short*)abits);
    k_attn_pv<<<dim3(16, 12, 4), 128, 0, stream>>>(abits, y2s, obt);
    k_mproj<<<dim3(128, 6), 256, 0, stream>>>(obt, Wp3, gamma2, beta2, x, out);
}

// Round 12
// 243.141 us; speedup vs baseline: 1.1507x; 1.0117x over previous
//
#include <hip/hip_runtime.h>
#include <hip/hip_bf16.h>
#include <math.h>

// R19: k_attn_pv TLP doubled. R18 counters: pv is the top kernel (73us),
// latency-bound (MfmaUtil 4.9, VALU 10.7, HBM 9.2, occupancy 16% = 1.5
// waves/SIMD) with no barriers -> wave starvation, not phase overhead.
// Split m-range: 2 mi-tiles/wave (was 4), grid (32,12,4) = 1536 blocks =
// 12 waves/CU (3/SIMD). Per-output math/order/ownership unchanged ->
// bit-exact. ay re-reads are L2-resident (48KB slab shared by 32 blocks).
// Everything else identical to R18.

typedef __attribute__((ext_vector_type(8))) short short8;
typedef __attribute__((ext_vector_type(4))) float f32x4;

#define T_ 4
#define B_ 4
#define C_ 384
#define HW 1024
#define NH_ 12
#define Np_ 256
#define EPS_ 1e-5f

static __device__ __forceinline__ unsigned short f2bf(float f) {
    __hip_bfloat16 h = __float2bfloat16(f);
    return *reinterpret_cast<unsigned short*>(&h);
}
static __device__ __forceinline__ float bf2f(unsigned short u) {
    __hip_bfloat16 h = *reinterpret_cast<__hip_bfloat16*>(&u);
    return __bfloat162float(h);
}
static __device__ __forceinline__ void split3(float w, unsigned short& u0,
                                              unsigned short& u1, unsigned short& u2) {
    u0 = f2bf(w);  float f0 = bf2f(u0);
    float r1 = w - f0;
    u1 = f2bf(r1); float f1 = bf2f(u1);
    u2 = f2bf(r1 - f1);
}

// ---------------- K_pre: wsplit (blocks 0..5183) + lif_im2col (blocks 5184..6719) ----
__global__ __launch_bounds__(256) void k_pre(const float* __restrict__ Wc,
                                             const float* __restrict__ Wp,
                                             const float* __restrict__ x,
                                             unsigned short* __restrict__ Wc3,
                                             unsigned short* __restrict__ Wp3,
                                             unsigned short* __restrict__ Bc,
                                             unsigned short* __restrict__ xsb) {
    if (blockIdx.x < 5184) {
        const int NC = 768 * 1536;
        const int NP = 384 * 384;
        int i = blockIdx.x * 256 + threadIdx.x;
        float w; unsigned short* dst; int idx, plane;
        if (i < NC) { w = Wc[i]; dst = Wc3; idx = i; plane = NC; }
        else {
            int j = i - NC;
            if (j >= NP) return;
            w = Wp[j]; dst = Wp3; idx = j; plane = NP;
        }
        unsigned short u0, u1, u2;
        split3(w, u0, u1, u2);
        dst[idx] = u0; dst[plane + idx] = u1; dst[2 * plane + idx] = u2;
    } else {
        int gt = (blockIdx.x - 5184) * 256 + threadIdx.x;
        int pw = gt & 15, ph = (gt >> 4) & 15;
        int v = gt >> 8;
        int c = v % 384, b = v / 384;
        float v00 = 0.f, v01 = 0.f, v10 = 0.f, v11 = 0.f;
        const size_t xrow = ((size_t)b * C_ + c) * HW + (size_t)(2 * ph) * 32 + 2 * pw;
#pragma unroll
        for (int t = 0; t < T_; ++t) {
            const float* px = x + (size_t)t * (B_ * C_ * HW) + xrow;
            float2 r0 = *(const float2*)px;
            float2 r1 = *(const float2*)(px + 32);
            v00 += (r0.x - v00) * 0.5f;
            v01 += (r0.y - v01) * 0.5f;
            v10 += (r1.x - v10) * 0.5f;
            v11 += (r1.y - v11) * 0.5f;
            ushort4 s;
            s.x = (v00 >= 1.f) ? 0x3F80 : 0; if (v00 >= 1.f) v00 = 0.f;
            s.y = (v01 >= 1.f) ? 0x3F80 : 0; if (v01 >= 1.f) v01 = 0.f;
            s.z = (v10 >= 1.f) ? 0x3F80 : 0; if (v10 >= 1.f) v10 = 0.f;
            s.w = (v11 >= 1.f) ? 0x3F80 : 0; if (v11 >= 1.f) v11 = 0.f;
            int tb = t * B_ + b;
            int n = tb * 256 + ph * 16 + pw;
            *(ushort4*)(Bc + (size_t)n * 1536 + 4 * c) = s;
            size_t xo = ((size_t)tb * C_ + c) * HW + (size_t)(2 * ph) * 32 + 2 * pw;
            ushort2 w0 = {s.x, s.y}, w1 = {s.z, s.w};
            *(ushort2*)(xsb + xo) = w0;
            *(ushort2*)(xsb + xo + 32) = w1;
        }
    }
}

// ---------------- K2: conv GEMM via MFMA (R16 triple-buffer, proven 45.4us) ----------
#define GL16(GP, LP) __builtin_amdgcn_global_load_lds(                        \
    (const __attribute__((address_space(1))) void*)(GP),                      \
    (__attribute__((address_space(3))) void*)(LP), 16, 0, 0)

static __device__ __forceinline__ void stage_conv(const unsigned short* __restrict__ Wc3,
                                                  const unsigned short* __restrict__ Bc,
                                                  short* smb, int mb, int nb, int k0,
                                                  int wid, int rloc, int cswz) {
    if (wid == 0) {
#pragma unroll
        for (int s = 0; s < 3; ++s)
#pragma unroll
            for (int u = 0; u < 2; ++u)
                GL16(Wc3 + ((size_t)(s * 768 + mb * 32 + u * 16 + rloc)) * 1536 + k0 + cswz * 8,
                     smb + s * 1024 + u * 512);
        GL16(Bc + ((size_t)(nb * 128 + rloc)) * 1536 + k0 + cswz * 8, smb + 3072);
    } else {
#pragma unroll
        for (int v = 1; v < 8; ++v)
            GL16(Bc + ((size_t)(nb * 128 + v * 16 + rloc)) * 1536 + k0 + cswz * 8,
                 smb + 3072 + v * 512);
    }
}

__global__ __launch_bounds__(128) void k_mconv(const unsigned short* __restrict__ Bc,
                                               const unsigned short* __restrict__ Wc3,
                                               const float* __restrict__ g1,
                                               const float* __restrict__ b1,
                                               const float* __restrict__ frx,
                                               const float* __restrict__ fra,
                                               unsigned short* __restrict__ y1s,
                                               unsigned short* __restrict__ y2s) {
    __shared__ short sm[3][7168];
    const int nb = blockIdx.x, mb = blockIdx.y;
    const int tid = threadIdx.x;
    const int lane = tid & 63, wid = tid >> 6;
    const int quad = lane >> 4, lr = lane & 15;
    const int rloc = lane >> 2;
    const int cswz = (lane & 3) ^ ((lane >> 3) & 3);
    const int slot = quad ^ ((lr >> 1) & 3);
    const int wn = wid;

    f32x4 acc[2][4];
#pragma unroll
    for (int im = 0; im < 2; ++im)
#pragma unroll
        for (int in = 0; in < 4; ++in)
            acc[im][in] = (f32x4){0.f, 0.f, 0.f, 0.f};

    stage_conv(Wc3, Bc, sm[0], mb, nb, 0, wid, rloc, cswz);
    stage_conv(Wc3, Bc, sm[1], mb, nb, 32, wid, rloc, cswz);

#pragma unroll 3
    for (int kt = 0; kt < 48; ++kt) {
        if (kt < 47) { asm volatile("s_waitcnt vmcnt(7)" ::: "memory"); }
        else         { asm volatile("s_waitcnt vmcnt(0)" ::: "memory"); }
        asm volatile("" ::: "memory");
        __builtin_amdgcn_s_barrier();
        __builtin_amdgcn_sched_barrier(0);

        if (kt <= 45)
            stage_conv(Wc3, Bc, sm[(kt + 2) % 3], mb, nb, (kt + 2) * 32, wid, rloc, cswz);

        const short* smb = sm[kt % 3];
        short8 af[3][2], bf[4];
#pragma unroll
        for (int s = 0; s < 3; ++s)
#pragma unroll
            for (int im = 0; im < 2; ++im)
                af[s][im] = *(const short8*)&smb[s * 1024 + (im * 16 + lr) * 32 + slot * 8];
#pragma unroll
        for (int in = 0; in < 4; ++in)
            bf[in] = *(const short8*)&smb[3072 + (wn * 64 + in * 16 + lr) * 32 + slot * 8];

#pragma unroll
        for (int s = 0; s < 3; ++s)
#pragma unroll
            for (int im = 0; im < 2; ++im)
#pragma unroll
                for (int in = 0; in < 4; ++in)
                    acc[im][in] = __builtin_amdgcn_mfma_f32_16x16x32_bf16(af[s][im], bf[in], acc[im][in], 0, 0, 0);
    }

    const float rs = 1.0f / sqrtf(1.0f + EPS_);
    const int h = mb >> 1, half = mb & 1;
    const float scl = (half == 0) ? (1.0f / sqrtf(frx[h] * 32.0f))
                                  : (1.0f / sqrtf(fra[h] * 256.0f));
    unsigned short* dst = (half == 0) ? y1s : y2s;
#pragma unroll
    for (int im = 0; im < 2; ++im) {
#pragma unroll
        for (int in = 0; in < 4; ++in) {
            int n_g = nb * 128 + wn * 64 + in * 16 + lr;
            int tb = n_g >> 8, pn = n_g & 255;
            size_t base = (size_t)(tb * NH_ + h) * 3 * 8192;
            ushort4 o0, o1, o2;
#pragma unroll
            for (int r = 0; r < 4; ++r) {
                int oc = mb * 32 + im * 16 + quad * 4 + r;
                float val = (acc[im][in][r] * (g1[oc] * rs) + b1[oc]) * scl;
                unsigned short u0, u1, u2;
                split3(val, u0, u1, u2);
                ((unsigned short*)&o0)[r] = u0;
                ((unsigned short*)&o1)[r] = u1;
                ((unsigned short*)&o2)[r] = u2;
            }
            int dd = im * 16 + quad * 4;
            if (half == 0) {
                *(ushort4*)&dst[base + 0 * 8192 + (size_t)pn * 32 + dd] = o0;
                *(ushort4*)&dst[base + 1 * 8192 + (size_t)pn * 32 + dd] = o1;
                *(ushort4*)&dst[base + 2 * 8192 + (size_t)pn * 32 + dd] = o2;
            } else {
#pragma unroll
                for (int r = 0; r < 4; ++r) {
                    dst[base + 0 * 8192 + (size_t)(dd + r) * 256 + pn] = ((unsigned short*)&o0)[r];
                    dst[base + 1 * 8192 + (size_t)(dd + r) * 256 + pn] = ((unsigned short*)&o1)[r];
                    dst[base + 2 * 8192 + (size_t)(dd + r) * 256 + pn] = ((unsigned short*)&o2)[r];
                }
            }
        }
    }
}

// ---------------- K3a: ein1 + attn-LIF -> packed spike bits ----------------
__global__ __launch_bounds__(256, 2) void k_attn_qk(const unsigned short* __restrict__ xsb,
                                                    const unsigned short* __restrict__ y1s,
                                                    unsigned short* __restrict__ abq) {
    __shared__ unsigned short xb[4][64][40];   // [t][m][d] : 20,480 B
    const int h = blockIdx.y, b = blockIdx.z;
    const int tid = threadIdx.x;
    const int lane = tid & 63, wq = tid >> 6;
    const int quad = lane >> 4, lr = lane & 15;
    const int m0 = blockIdx.x * 64;

#pragma unroll
    for (int i = 0; i < 8; ++i) {
        int e = tid + i * 256;                 // 2048 ushort4 = 4t*64m*32d
        int j4 = e & 15, d = (e >> 4) & 31, t = e >> 9;
        ushort4 v = *(const ushort4*)(xsb + ((size_t)((t * B_ + b) * C_) + h * 32 + d) * HW + m0 + j4 * 4);
        int key = (j4 ^ (j4 >> 2)) & 3;
        int cc = ((((d >> 3) ^ key) << 3) | (d & 7));
        xb[t][j4 * 4 + 0][cc] = v.x;
        xb[t][j4 * 4 + 1][cc] = v.y;
        xb[t][j4 * 4 + 2][cc] = v.z;
        xb[t][j4 * 4 + 3][cc] = v.w;
    }
    __syncthreads();   // only barrier; t/m loops below are wave-autonomous

    float vat[4][4][4];   // [mi][itl][r] attn-LIF state
#pragma unroll
    for (int mi = 0; mi < 4; ++mi)
#pragma unroll
        for (int itl = 0; itl < 4; ++itl)
#pragma unroll
            for (int r = 0; r < 4; ++r) vat[mi][itl][r] = 0.f;

#pragma unroll
    for (int t = 0; t < T_; ++t) {
        const int tb = t * B_ + b;
        const size_t slab = (size_t)(tb * NH_ + h) * 3 * 8192;

        // m-invariant A-fragments: 12 loads, reused by all 4 m-tiles
        short8 af[3][4];
        const unsigned short* y1p = y1s + slab + (size_t)(wq * 64 + lr) * 32 + quad * 8;
#pragma unroll
        for (int s = 0; s < 3; ++s)
#pragma unroll
            for (int itl = 0; itl < 4; ++itl)
                af[s][itl] = *(const short8*)(y1p + s * 8192 + itl * 512);

#pragma unroll
        for (int mi = 0; mi < 4; ++mi) {
            int keyr = ((lr >> 2) ^ mi) & 3;
            short8 bx = *(const short8*)&xb[t][mi * 16 + lr][(quad ^ keyr) * 8];
            f32x4 acc[4];
#pragma unroll
            for (int itl = 0; itl < 4; ++itl) acc[itl] = (f32x4){0.f, 0.f, 0.f, 0.f};
#pragma unroll
            for (int s = 0; s < 3; ++s)
#pragma unroll
                for (int itl = 0; itl < 4; ++itl)
                    acc[itl] = __builtin_amdgcn_mfma_f32_16x16x32_bf16(af[s][itl], bx, acc[itl], 0, 0, 0);

            unsigned int q = 0;
#pragma unroll
            for (int itl = 0; itl < 4; ++itl)
#pragma unroll
                for (int r = 0; r < 4; ++r) {
                    float v = vat[mi][itl][r];
                    v += (acc[itl][r] - v) * 0.5f;
                    bool s = (v >= 1.0f);
                    vat[mi][itl][r] = s ? 0.f : v;
                    q |= (s ? 1u : 0u) << (itl * 4 + r);
                }
            int m = m0 + mi * 16 + lr;
            abq[(((size_t)(tb * NH_ + h) * 1024 + m) * 4 + quad) * 4 + wq] = (unsigned short)q;
        }
    }
}

// ---------------- K3b: ein2 + out-LIF (no LDS, no barriers) ----------------
// R19: 2 mi-tiles per wave, grid (32,12,4) = 1536 blocks = 12 waves/CU
// (was 16 blocks_x x 4 mi = 6 waves/CU). Same per-output math/order.
__global__ __launch_bounds__(128) void k_attn_pv(const unsigned long long* __restrict__ abits,
                                                 const unsigned short* __restrict__ y2s,
                                                 unsigned short* __restrict__ obt) {
    const int h = blockIdx.y, b = blockIdx.z;
    const int tid = threadIdx.x;
    const int lane = tid & 63;
    const int quad = lane >> 4, lr = lane & 15;
    const int dt = tid >> 6;                     // wave id = d-half owner
    const int mbase = blockIdx.x * 32;
    const int obase = (quad & 2) << 1;   // 0 or 4

    float vo[2][4];
#pragma unroll
    for (int mi = 0; mi < 2; ++mi)
#pragma unroll
        for (int r = 0; r < 4; ++r) vo[mi][r] = 0.f;

#pragma unroll
    for (int t = 0; t < T_; ++t) {
        const int tb = t * B_ + b;
        const size_t slab = (size_t)(tb * NH_ + h) * 3 * 8192;

        // m-invariant A-fragments: 24 loads, reused by both m-tiles
        short8 ay[3][8];
        const unsigned short* y2p = y2s + slab + (size_t)(dt * 16 + lr) * 256 + quad * 8;
#pragma unroll
        for (int s = 0; s < 3; ++s)
#pragma unroll
            for (int kt = 0; kt < 8; ++kt)
                ay[s][kt] = *(const short8*)(y2p + s * 8192 + kt * 32);

#pragma unroll
        for (int mi = 0; mi < 2; ++mi) {
            const int m = mbase + mi * 16 + lr;
            const unsigned long long* ap = abits + ((size_t)(tb * NH_ + h) * 1024 + m) * 4 + (quad & 1) * 2;
            unsigned long long Qa = ap[0];
            unsigned long long Qb = ap[1];

            short8 bs[8];
#pragma unroll
            for (int kt = 0; kt < 8; ++kt) {
                int o = kt * 8 + obase;
                unsigned int a4 = (unsigned int)(Qa >> o) & 15u;
                unsigned int b4 = (unsigned int)(Qb >> o) & 15u;
                union { short8 v; unsigned int w[4]; } u;
                u.w[0] = ((a4 & 1u) ? 0x3F80u : 0u) | ((a4 & 2u) ? 0x3F800000u : 0u);
                u.w[1] = ((a4 & 4u) ? 0x3F80u : 0u) | ((a4 & 8u) ? 0x3F800000u : 0u);
                u.w[2] = ((b4 & 1u) ? 0x3F80u : 0u) | ((b4 & 2u) ? 0x3F800000u : 0u);
                u.w[3] = ((b4 & 4u) ? 0x3F80u : 0u) | ((b4 & 8u) ? 0x3F800000u : 0u);
                bs[kt] = u.v;
            }

            f32x4 acc2 = (f32x4){0.f, 0.f, 0.f, 0.f};
#pragma unroll
            for (int s = 0; s < 3; ++s)
#pragma unroll
                for (int kt = 0; kt < 8; ++kt)
                    acc2 = __builtin_amdgcn_mfma_f32_16x16x32_bf16(ay[s][kt], bs[kt], acc2, 0, 0, 0);

            ushort4 ob;
#pragma unroll
            for (int r = 0; r < 4; ++r) {
                float v = vo[mi][r];
                v += (acc2[r] - v) * 0.5f;
                bool s = (v >= 1.0f);
                ((unsigned short*)&ob)[r] = s ? 0x3F80 : 0;
                vo[mi][r] = s ? 0.f : v;
            }
            *(ushort4*)(obt + ((size_t)tb * HW + m) * C_ + h * 32 + dt * 16 + quad * 4) = ob;
        }
    }
}

// ---------------- K4: proj GEMM via MFMA + BN2 + residual (R13 async) ----------------
static __device__ __forceinline__ void stage_proj(const unsigned short* __restrict__ Wp3,
                                                  const unsigned short* __restrict__ obt,
                                                  short* smb, int mb, int nb, int k0,
                                                  int wid, int rloc, int cswz) {
    if (wid < 3) {
#pragma unroll
        for (int u = 0; u < 4; ++u)
            GL16(Wp3 + ((size_t)(wid * 384 + mb * 64 + u * 16 + rloc)) * 384 + k0 + cswz * 8,
                 smb + wid * 2048 + u * 512);
        GL16(obt + ((size_t)(nb * 128 + wid * 16 + rloc)) * 384 + k0 + cswz * 8,
             smb + 6144 + wid * 512);
    } else {
#pragma unroll
        for (int v = 3; v < 8; ++v)
            GL16(obt + ((size_t)(nb * 128 + v * 16 + rloc)) * 384 + k0 + cswz * 8,
                 smb + 6144 + v * 512);
    }
}

__global__ __launch_bounds__(256) void k_mproj(const unsigned short* __restrict__ obt,
                                               const unsigned short* __restrict__ Wp3,
                                               const float* __restrict__ g2,
                                               const float* __restrict__ b2,
                                               const float* __restrict__ x,
                                               float* __restrict__ out) {
    __shared__ short sm[2][10240];
    const int nb = blockIdx.x, mb = blockIdx.y;
    const int tid = threadIdx.x;
    const int lane = tid & 63, wave = tid >> 6;
    const int wm = wave >> 1, wn = wave & 1;
    const int quad = lane >> 4, lr = lane & 15;
    const int rloc = lane >> 2;
    const int cswz = (lane & 3) ^ ((lane >> 3) & 3);
    const int slot = quad ^ ((lr >> 1) & 3);

    f32x4 acc[2][4];
#pragma unroll
    for (int im = 0; im < 2; ++im)
#pragma unroll
        for (int in = 0; in < 4; ++in)
            acc[im][in] = (f32x4){0.f, 0.f, 0.f, 0.f};

    stage_proj(Wp3, obt, sm[0], mb, nb, 0, wave, rloc, cswz);

    for (int kt = 0; kt < 12; ++kt) {
        const int b = kt & 1;
        if (kt < 11) {
            stage_proj(Wp3, obt, sm[b ^ 1], mb, nb, (kt + 1) * 32, wave, rloc, cswz);
            asm volatile("s_waitcnt vmcnt(5)" ::: "memory");
        } else {
            asm volatile("s_waitcnt vmcnt(0)" ::: "memory");
        }
        __builtin_amdgcn_s_barrier();
        __builtin_amdgcn_sched_barrier(0);

        const short* smb = sm[b];
        short8 af[3][2], bf[4];
#pragma unroll
        for (int s = 0; s < 3; ++s)
#pragma unroll
            for (int im = 0; im < 2; ++im)
                af[s][im] = *(const short8*)&smb[s * 2048 + (wm * 32 + im * 16 + lr) * 32 + slot * 8];
#pragma unroll
        for (int in = 0; in < 4; ++in)
            bf[in] = *(const short8*)&smb[6144 + (wn * 64 + in * 16 + lr) * 32 + slot * 8];
        asm volatile("s_waitcnt lgkmcnt(0)" ::: "memory");
        __builtin_amdgcn_sched_barrier(0);
        __builtin_amdgcn_s_barrier();
        __builtin_amdgcn_sched_barrier(0);

#pragma unroll
        for (int s = 0; s < 3; ++s)
#pragma unroll
            for (int im = 0; im < 2; ++im)
#pragma unroll
                for (int in = 0; in < 4; ++in)
                    acc[im][in] = __builtin_amdgcn_mfma_f32_16x16x32_bf16(af[s][im], bf[in], acc[im][in], 0, 0, 0);
    }

    const float rs = 1.0f / sqrtf(1.0f + EPS_);
#pragma unroll
    for (int im = 0; im < 2; ++im) {
#pragma unroll
        for (int in = 0; in < 4; ++in) {
            int n_g = nb * 128 + wn * 64 + in * 16 + lr;
            int tb = n_g >> 10, hw = n_g & 1023;
#pragma unroll
            for (int r = 0; r < 4; ++r) {
                int o = mb * 64 + wm * 32 + im * 16 + quad * 4 + r;
                size_t idx = ((size_t)tb * C_ + o) * HW + hw;
                out[idx] = acc[im][in][r] * (g2[o] * rs) + b2[o] + x[idx];
            }
        }
    }
}

extern "C" void kernel_launch(void* const* d_in, const int* in_sizes, int n_in,
                              void* d_out, int out_size, void* d_ws, size_t ws_size,
                              hipStream_t stream) {
    const float* x      = (const float*)d_in[0];
    const float* Wconv  = (const float*)d_in[1];
    const float* gamma1 = (const float*)d_in[2];
    const float* beta1  = (const float*)d_in[3];
    const float* Wproj  = (const float*)d_in[4];
    const float* gamma2 = (const float*)d_in[5];
    const float* beta2  = (const float*)d_in[6];
    const float* frx    = (const float*)d_in[7];
    const float* fra    = (const float*)d_in[8];
    float* out = (float*)d_out;

    unsigned short* ws16 = (unsigned short*)d_ws;
    unsigned short* Bc  = ws16;                 // aliased by obt after k_mconv
    unsigned short* obt = ws16;
    unsigned short* Wc3 = ws16 + 6291456;
    unsigned short* Wp3 = ws16 + 9830400;
    unsigned short* xsb = ws16 + 10272768;
    unsigned short* y1s = ws16 + 16564224;
    unsigned short* y2s = ws16 + 21282816;
    unsigned long long* abits = (unsigned long long*)(ws16 + 26001408);  // 6.3 MB

    k_pre<<<6720, 256, 0, stream>>>(Wconv, Wproj, x, Wc3, Wp3, Bc, xsb);
    k_mconv<<<dim3(32, 24), 128, 0, stream>>>(Bc, Wc3, gamma1, beta1, frx, fra, y1s, y2s);
    k_attn_qk<<<dim3(16, 12, 4), 256, 0, stream>>>(xsb, y1s, (unsigned short*)abits);
    k_attn_pv<<<dim3(32, 12, 4), 128, 0, stream>>>(abits, y2s, obt);
    k_mproj<<<dim3(128, 6), 256, 0, stream>>>(obt, Wp3, gamma2, beta2, x, out);
}

// Round 13
// 241.755 us; speedup vs baseline: 1.1573x; 1.0057x over previous
//
#include <hip/hip_runtime.h>
#include <hip/hip_bf16.h>
#include <math.h>

// R20: k_mconv BK 32 -> 64 (phase-count halving). Fixed-overhead model from
// R9/R14/R16 data: ~1450 cyc/phase overhead + ~770 cyc work, 48 phases = 44us
// (matches). R14 halved work/phase (lost, as model predicts); R20 doubles it:
// 24 phases x (1450 + 1540) ~= 30us. 2-barrier R9 loop, double-buffered
// 2x28.7KB LDS (2 blocks/CU). 128B rows need the 8-chunk involution
// chunk' = chunk ^ (row&7): src cswz=(lane&7)^(lane>>3) (within-row permute,
// coalescing intact); read slot=(kk*4+quad)^(lr&7) -> every aligned 8-lane
// group covers all 32 banks (conflict-free, same model as R9's measured 0).
// Staging 28 GL16/phase = 14/wave exactly -> uniform vmcnt(14).
// MFMA order kk0{s0,s1,s2},kk1{s0,s1,s2} == two old phases -> bit-exact.
// All other kernels identical to R19.

typedef __attribute__((ext_vector_type(8))) short short8;
typedef __attribute__((ext_vector_type(4))) float f32x4;

#define T_ 4
#define B_ 4
#define C_ 384
#define HW 1024
#define NH_ 12
#define Np_ 256
#define EPS_ 1e-5f

static __device__ __forceinline__ unsigned short f2bf(float f) {
    __hip_bfloat16 h = __float2bfloat16(f);
    return *reinterpret_cast<unsigned short*>(&h);
}
static __device__ __forceinline__ float bf2f(unsigned short u) {
    __hip_bfloat16 h = *reinterpret_cast<__hip_bfloat16*>(&u);
    return __bfloat162float(h);
}
static __device__ __forceinline__ void split3(float w, unsigned short& u0,
                                              unsigned short& u1, unsigned short& u2) {
    u0 = f2bf(w);  float f0 = bf2f(u0);
    float r1 = w - f0;
    u1 = f2bf(r1); float f1 = bf2f(u1);
    u2 = f2bf(r1 - f1);
}

// ---------------- K_pre: wsplit (blocks 0..5183) + lif_im2col (blocks 5184..6719) ----
__global__ __launch_bounds__(256) void k_pre(const float* __restrict__ Wc,
                                             const float* __restrict__ Wp,
                                             const float* __restrict__ x,
                                             unsigned short* __restrict__ Wc3,
                                             unsigned short* __restrict__ Wp3,
                                             unsigned short* __restrict__ Bc,
                                             unsigned short* __restrict__ xsb) {
    if (blockIdx.x < 5184) {
        const int NC = 768 * 1536;
        const int NP = 384 * 384;
        int i = blockIdx.x * 256 + threadIdx.x;
        float w; unsigned short* dst; int idx, plane;
        if (i < NC) { w = Wc[i]; dst = Wc3; idx = i; plane = NC; }
        else {
            int j = i - NC;
            if (j >= NP) return;
            w = Wp[j]; dst = Wp3; idx = j; plane = NP;
        }
        unsigned short u0, u1, u2;
        split3(w, u0, u1, u2);
        dst[idx] = u0; dst[plane + idx] = u1; dst[2 * plane + idx] = u2;
    } else {
        int gt = (blockIdx.x - 5184) * 256 + threadIdx.x;
        int pw = gt & 15, ph = (gt >> 4) & 15;
        int v = gt >> 8;
        int c = v % 384, b = v / 384;
        float v00 = 0.f, v01 = 0.f, v10 = 0.f, v11 = 0.f;
        const size_t xrow = ((size_t)b * C_ + c) * HW + (size_t)(2 * ph) * 32 + 2 * pw;
#pragma unroll
        for (int t = 0; t < T_; ++t) {
            const float* px = x + (size_t)t * (B_ * C_ * HW) + xrow;
            float2 r0 = *(const float2*)px;
            float2 r1 = *(const float2*)(px + 32);
            v00 += (r0.x - v00) * 0.5f;
            v01 += (r0.y - v01) * 0.5f;
            v10 += (r1.x - v10) * 0.5f;
            v11 += (r1.y - v11) * 0.5f;
            ushort4 s;
            s.x = (v00 >= 1.f) ? 0x3F80 : 0; if (v00 >= 1.f) v00 = 0.f;
            s.y = (v01 >= 1.f) ? 0x3F80 : 0; if (v01 >= 1.f) v01 = 0.f;
            s.z = (v10 >= 1.f) ? 0x3F80 : 0; if (v10 >= 1.f) v10 = 0.f;
            s.w = (v11 >= 1.f) ? 0x3F80 : 0; if (v11 >= 1.f) v11 = 0.f;
            int tb = t * B_ + b;
            int n = tb * 256 + ph * 16 + pw;
            *(ushort4*)(Bc + (size_t)n * 1536 + 4 * c) = s;
            size_t xo = ((size_t)tb * C_ + c) * HW + (size_t)(2 * ph) * 32 + 2 * pw;
            ushort2 w0 = {s.x, s.y}, w1 = {s.z, s.w};
            *(ushort2*)(xsb + xo) = w0;
            *(ushort2*)(xsb + xo + 32) = w1;
        }
    }
}

// ---------------- K2: conv GEMM via MFMA, BK=64 double-buffer ----------
#define GL16(GP, LP) __builtin_amdgcn_global_load_lds(                        \
    (const __attribute__((address_space(1))) void*)(GP),                      \
    (__attribute__((address_space(3))) void*)(LP), 16, 0, 0)

// LDS per buffer (shorts): A[3][32][64] at 0..6143, B[128][64] at 6144..14335.
// LDS[row][c'] holds global chunk c' ^ (row&7) (8 x 16B chunks per 128B row).
static __device__ __forceinline__ void stage_conv64(const unsigned short* __restrict__ Wc3,
                                                    const unsigned short* __restrict__ Bc,
                                                    short* smb, int mb, int nb, int k0,
                                                    int wid, int rloc8, int cswz8) {
    if (wid == 0) {
        // A: 12 segments (8 rows each) + B segments 0..1  -> 14 loads
#pragma unroll
        for (int a = 0; a < 12; ++a) {
            int s = a >> 2, rb = (a & 3) * 8;
            GL16(Wc3 + ((size_t)(s * 768 + mb * 32 + rb + rloc8)) * 1536 + k0 + cswz8 * 8,
                 smb + s * 2048 + (a & 3) * 512);
        }
#pragma unroll
        for (int v = 0; v < 2; ++v)
            GL16(Bc + ((size_t)(nb * 128 + v * 8 + rloc8)) * 1536 + k0 + cswz8 * 8,
                 smb + 6144 + v * 512);
    } else {
        // B segments 2..15 -> 14 loads
#pragma unroll
        for (int v = 2; v < 16; ++v)
            GL16(Bc + ((size_t)(nb * 128 + v * 8 + rloc8)) * 1536 + k0 + cswz8 * 8,
                 smb + 6144 + v * 512);
    }
    // exactly 14 global_load_lds per wave per call -> counted vmcnt(14).
}

__global__ __launch_bounds__(128) void k_mconv(const unsigned short* __restrict__ Bc,
                                               const unsigned short* __restrict__ Wc3,
                                               const float* __restrict__ g1,
                                               const float* __restrict__ b1,
                                               const float* __restrict__ frx,
                                               const float* __restrict__ fra,
                                               unsigned short* __restrict__ y1s,
                                               unsigned short* __restrict__ y2s) {
    __shared__ short sm[2][14336];                // 2 x 28,672 B = 57,344 B (2 blk/CU)
    const int nb = blockIdx.x, mb = blockIdx.y;   // nb: 0..31 (N/128), mb: 0..23 (M/32)
    const int tid = threadIdx.x;
    const int lane = tid & 63, wid = tid >> 6;    // 2 waves; wave = N-half owner
    const int quad = lane >> 4, lr = lane & 15;
    const int rloc8 = lane >> 3;                  // staging: 8 lanes per 128B row
    const int cswz8 = (lane & 7) ^ rloc8;         // source chunk swizzle (8 chunks)
    const int lk = lr & 7;                        // read-side swizzle key
    const int wn = wid;

    f32x4 acc[2][4];
#pragma unroll
    for (int im = 0; im < 2; ++im)
#pragma unroll
        for (int in = 0; in < 4; ++in)
            acc[im][in] = (f32x4){0.f, 0.f, 0.f, 0.f};

    stage_conv64(Wc3, Bc, sm[0], mb, nb, 0, wid, rloc8, cswz8);   // phase 0

#pragma unroll 2
    for (int kt = 0; kt < 24; ++kt) {
        const int b = kt & 1;
        if (kt < 23) {
            stage_conv64(Wc3, Bc, sm[b ^ 1], mb, nb, (kt + 1) * 64, wid, rloc8, cswz8);
            asm volatile("s_waitcnt vmcnt(14)" ::: "memory");   // cur done, next in flight
        } else {
            asm volatile("s_waitcnt vmcnt(0)" ::: "memory");
        }
        __builtin_amdgcn_s_barrier();             // cur buffer visible to both waves
        __builtin_amdgcn_sched_barrier(0);        // pin: nothing crosses upward

        const short* smb = sm[b];
        short8 af[2][3][2], bf[2][4];
#pragma unroll
        for (int kk = 0; kk < 2; ++kk) {
            const int sl = ((kk << 2) | quad) ^ lk;   // chunk slot 0..7
#pragma unroll
            for (int s = 0; s < 3; ++s)
#pragma unroll
                for (int im = 0; im < 2; ++im)
                    af[kk][s][im] = *(const short8*)&smb[s * 2048 + (im * 16 + lr) * 64 + sl * 8];
#pragma unroll
            for (int in = 0; in < 4; ++in)
                bf[kk][in] = *(const short8*)&smb[6144 + (wn * 64 + in * 16 + lr) * 64 + sl * 8];
        }
        asm volatile("s_waitcnt lgkmcnt(0)" ::: "memory");  // reads done before WAR barrier
        __builtin_amdgcn_sched_barrier(0);        // pin: no ds_read sinks below wait
        __builtin_amdgcn_s_barrier();             // all waves done reading buf b
        __builtin_amdgcn_sched_barrier(0);        // pin: no stage hoists above barrier

#pragma unroll
        for (int kk = 0; kk < 2; ++kk)            // == two consecutive old phases
#pragma unroll
            for (int s = 0; s < 3; ++s)
#pragma unroll
                for (int im = 0; im < 2; ++im)
#pragma unroll
                    for (int in = 0; in < 4; ++in)
                        acc[im][in] = __builtin_amdgcn_mfma_f32_16x16x32_bf16(af[kk][s][im], bf[kk][in], acc[im][in], 0, 0, 0);
    }

    const float rs = 1.0f / sqrtf(1.0f + EPS_);
    const int h = mb >> 1, half = mb & 1;         // mb*32 = h*64 + half*32
    const float scl = (half == 0) ? (1.0f / sqrtf(frx[h] * 32.0f))
                                  : (1.0f / sqrtf(fra[h] * 256.0f));
    unsigned short* dst = (half == 0) ? y1s : y2s;
#pragma unroll
    for (int im = 0; im < 2; ++im) {
#pragma unroll
        for (int in = 0; in < 4; ++in) {
            int n_g = nb * 128 + wn * 64 + in * 16 + lr;
            int tb = n_g >> 8, pn = n_g & 255;
            size_t base = (size_t)(tb * NH_ + h) * 3 * 8192;
            ushort4 o0, o1, o2;
#pragma unroll
            for (int r = 0; r < 4; ++r) {
                int oc = mb * 32 + im * 16 + quad * 4 + r;
                float val = (acc[im][in][r] * (g1[oc] * rs) + b1[oc]) * scl;
                unsigned short u0, u1, u2;
                split3(val, u0, u1, u2);
                ((unsigned short*)&o0)[r] = u0;
                ((unsigned short*)&o1)[r] = u1;
                ((unsigned short*)&o2)[r] = u2;
            }
            int dd = im * 16 + quad * 4;
            if (half == 0) {
                *(ushort4*)&dst[base + 0 * 8192 + (size_t)pn * 32 + dd] = o0;
                *(ushort4*)&dst[base + 1 * 8192 + (size_t)pn * 32 + dd] = o1;
                *(ushort4*)&dst[base + 2 * 8192 + (size_t)pn * 32 + dd] = o2;
            } else {
#pragma unroll
                for (int r = 0; r < 4; ++r) {
                    dst[base + 0 * 8192 + (size_t)(dd + r) * 256 + pn] = ((unsigned short*)&o0)[r];
                    dst[base + 1 * 8192 + (size_t)(dd + r) * 256 + pn] = ((unsigned short*)&o1)[r];
                    dst[base + 2 * 8192 + (size_t)(dd + r) * 256 + pn] = ((unsigned short*)&o2)[r];
                }
            }
        }
    }
}

// ---------------- K3a: ein1 + attn-LIF -> packed spike bits ----------------
__global__ __launch_bounds__(256, 2) void k_attn_qk(const unsigned short* __restrict__ xsb,
                                                    const unsigned short* __restrict__ y1s,
                                                    unsigned short* __restrict__ abq) {
    __shared__ unsigned short xb[4][64][40];   // [t][m][d] : 20,480 B
    const int h = blockIdx.y, b = blockIdx.z;
    const int tid = threadIdx.x;
    const int lane = tid & 63, wq = tid >> 6;
    const int quad = lane >> 4, lr = lane & 15;
    const int m0 = blockIdx.x * 64;

#pragma unroll
    for (int i = 0; i < 8; ++i) {
        int e = tid + i * 256;                 // 2048 ushort4 = 4t*64m*32d
        int j4 = e & 15, d = (e >> 4) & 31, t = e >> 9;
        ushort4 v = *(const ushort4*)(xsb + ((size_t)((t * B_ + b) * C_) + h * 32 + d) * HW + m0 + j4 * 4);
        int key = (j4 ^ (j4 >> 2)) & 3;
        int cc = ((((d >> 3) ^ key) << 3) | (d & 7));
        xb[t][j4 * 4 + 0][cc] = v.x;
        xb[t][j4 * 4 + 1][cc] = v.y;
        xb[t][j4 * 4 + 2][cc] = v.z;
        xb[t][j4 * 4 + 3][cc] = v.w;
    }
    __syncthreads();   // only barrier; t/m loops below are wave-autonomous

    float vat[4][4][4];   // [mi][itl][r] attn-LIF state
#pragma unroll
    for (int mi = 0; mi < 4; ++mi)
#pragma unroll
        for (int itl = 0; itl < 4; ++itl)
#pragma unroll
            for (int r = 0; r < 4; ++r) vat[mi][itl][r] = 0.f;

#pragma unroll
    for (int t = 0; t < T_; ++t) {
        const int tb = t * B_ + b;
        const size_t slab = (size_t)(tb * NH_ + h) * 3 * 8192;

        // m-invariant A-fragments: 12 loads, reused by all 4 m-tiles
        short8 af[3][4];
        const unsigned short* y1p = y1s + slab + (size_t)(wq * 64 + lr) * 32 + quad * 8;
#pragma unroll
        for (int s = 0; s < 3; ++s)
#pragma unroll
            for (int itl = 0; itl < 4; ++itl)
                af[s][itl] = *(const short8*)(y1p + s * 8192 + itl * 512);

#pragma unroll
        for (int mi = 0; mi < 4; ++mi) {
            int keyr = ((lr >> 2) ^ mi) & 3;
            short8 bx = *(const short8*)&xb[t][mi * 16 + lr][(quad ^ keyr) * 8];
            f32x4 acc[4];
#pragma unroll
            for (int itl = 0; itl < 4; ++itl) acc[itl] = (f32x4){0.f, 0.f, 0.f, 0.f};
#pragma unroll
            for (int s = 0; s < 3; ++s)
#pragma unroll
                for (int itl = 0; itl < 4; ++itl)
                    acc[itl] = __builtin_amdgcn_mfma_f32_16x16x32_bf16(af[s][itl], bx, acc[itl], 0, 0, 0);

            unsigned int q = 0;
#pragma unroll
            for (int itl = 0; itl < 4; ++itl)
#pragma unroll
                for (int r = 0; r < 4; ++r) {
                    float v = vat[mi][itl][r];
                    v += (acc[itl][r] - v) * 0.5f;
                    bool s = (v >= 1.0f);
                    vat[mi][itl][r] = s ? 0.f : v;
                    q |= (s ? 1u : 0u) << (itl * 4 + r);
                }
            int m = m0 + mi * 16 + lr;
            abq[(((size_t)(tb * NH_ + h) * 1024 + m) * 4 + quad) * 4 + wq] = (unsigned short)q;
        }
    }
}

// ---------------- K3b: ein2 + out-LIF (no LDS, no barriers) ----------------
// 2 mi-tiles per wave, grid (32,12,4) = 1536 blocks = 12 waves/CU.
__global__ __launch_bounds__(128) void k_attn_pv(const unsigned long long* __restrict__ abits,
                                                 const unsigned short* __restrict__ y2s,
                                                 unsigned short* __restrict__ obt) {
    const int h = blockIdx.y, b = blockIdx.z;
    const int tid = threadIdx.x;
    const int lane = tid & 63;
    const int quad = lane >> 4, lr = lane & 15;
    const int dt = tid >> 6;                     // wave id = d-half owner
    const int mbase = blockIdx.x * 32;
    const int obase = (quad & 2) << 1;   // 0 or 4

    float vo[2][4];
#pragma unroll
    for (int mi = 0; mi < 2; ++mi)
#pragma unroll
        for (int r = 0; r < 4; ++r) vo[mi][r] = 0.f;

#pragma unroll
    for (int t = 0; t < T_; ++t) {
        const int tb = t * B_ + b;
        const size_t slab = (size_t)(tb * NH_ + h) * 3 * 8192;

        // m-invariant A-fragments: 24 loads, reused by both m-tiles
        short8 ay[3][8];
        const unsigned short* y2p = y2s + slab + (size_t)(dt * 16 + lr) * 256 + quad * 8;
#pragma unroll
        for (int s = 0; s < 3; ++s)
#pragma unroll
            for (int kt = 0; kt < 8; ++kt)
                ay[s][kt] = *(const short8*)(y2p + s * 8192 + kt * 32);

#pragma unroll
        for (int mi = 0; mi < 2; ++mi) {
            const int m = mbase + mi * 16 + lr;
            const unsigned long long* ap = abits + ((size_t)(tb * NH_ + h) * 1024 + m) * 4 + (quad & 1) * 2;
            unsigned long long Qa = ap[0];
            unsigned long long Qb = ap[1];

            short8 bs[8];
#pragma unroll
            for (int kt = 0; kt < 8; ++kt) {
                int o = kt * 8 + obase;
                unsigned int a4 = (unsigned int)(Qa >> o) & 15u;
                unsigned int b4 = (unsigned int)(Qb >> o) & 15u;
                union { short8 v; unsigned int w[4]; } u;
                u.w[0] = ((a4 & 1u) ? 0x3F80u : 0u) | ((a4 & 2u) ? 0x3F800000u : 0u);
                u.w[1] = ((a4 & 4u) ? 0x3F80u : 0u) | ((a4 & 8u) ? 0x3F800000u : 0u);
                u.w[2] = ((b4 & 1u) ? 0x3F80u : 0u) | ((b4 & 2u) ? 0x3F800000u : 0u);
                u.w[3] = ((b4 & 4u) ? 0x3F80u : 0u) | ((b4 & 8u) ? 0x3F800000u : 0u);
                bs[kt] = u.v;
            }

            f32x4 acc2 = (f32x4){0.f, 0.f, 0.f, 0.f};
#pragma unroll
            for (int s = 0; s < 3; ++s)
#pragma unroll
                for (int kt = 0; kt < 8; ++kt)
                    acc2 = __builtin_amdgcn_mfma_f32_16x16x32_bf16(ay[s][kt], bs[kt], acc2, 0, 0, 0);

            ushort4 ob;
#pragma unroll
            for (int r = 0; r < 4; ++r) {
                float v = vo[mi][r];
                v += (acc2[r] - v) * 0.5f;
                bool s = (v >= 1.0f);
                ((unsigned short*)&ob)[r] = s ? 0x3F80 : 0;
                vo[mi][r] = s ? 0.f : v;
            }
            *(ushort4*)(obt + ((size_t)tb * HW + m) * C_ + h * 32 + dt * 16 + quad * 4) = ob;
        }
    }
}

// ---------------- K4: proj GEMM via MFMA + BN2 + residual (R13 async) ----------------
static __device__ __forceinline__ void stage_proj(const unsigned short* __restrict__ Wp3,
                                                  const unsigned short* __restrict__ obt,
                                                  short* smb, int mb, int nb, int k0,
                                                  int wid, int rloc, int cswz) {
    if (wid < 3) {
#pragma unroll
        for (int u = 0; u < 4; ++u)
            GL16(Wp3 + ((size_t)(wid * 384 + mb * 64 + u * 16 + rloc)) * 384 + k0 + cswz * 8,
                 smb + wid * 2048 + u * 512);
        GL16(obt + ((size_t)(nb * 128 + wid * 16 + rloc)) * 384 + k0 + cswz * 8,
             smb + 6144 + wid * 512);
    } else {
#pragma unroll
        for (int v = 3; v < 8; ++v)
            GL16(obt + ((size_t)(nb * 128 + v * 16 + rloc)) * 384 + k0 + cswz * 8,
                 smb + 6144 + v * 512);
    }
}

__global__ __launch_bounds__(256) void k_mproj(const unsigned short* __restrict__ obt,
                                               const unsigned short* __restrict__ Wp3,
                                               const float* __restrict__ g2,
                                               const float* __restrict__ b2,
                                               const float* __restrict__ x,
                                               float* __restrict__ out) {
    __shared__ short sm[2][10240];
    const int nb = blockIdx.x, mb = blockIdx.y;
    const int tid = threadIdx.x;
    const int lane = tid & 63, wave = tid >> 6;
    const int wm = wave >> 1, wn = wave & 1;
    const int quad = lane >> 4, lr = lane & 15;
    const int rloc = lane >> 2;
    const int cswz = (lane & 3) ^ ((lane >> 3) & 3);
    const int slot = quad ^ ((lr >> 1) & 3);

    f32x4 acc[2][4];
#pragma unroll
    for (int im = 0; im < 2; ++im)
#pragma unroll
        for (int in = 0; in < 4; ++in)
            acc[im][in] = (f32x4){0.f, 0.f, 0.f, 0.f};

    stage_proj(Wp3, obt, sm[0], mb, nb, 0, wave, rloc, cswz);

    for (int kt = 0; kt < 12; ++kt) {
        const int b = kt & 1;
        if (kt < 11) {
            stage_proj(Wp3, obt, sm[b ^ 1], mb, nb, (kt + 1) * 32, wave, rloc, cswz);
            asm volatile("s_waitcnt vmcnt(5)" ::: "memory");
        } else {
            asm volatile("s_waitcnt vmcnt(0)" ::: "memory");
        }
        __builtin_amdgcn_s_barrier();
        __builtin_amdgcn_sched_barrier(0);

        const short* smb = sm[b];
        short8 af[3][2], bf[4];
#pragma unroll
        for (int s = 0; s < 3; ++s)
#pragma unroll
            for (int im = 0; im < 2; ++im)
                af[s][im] = *(const short8*)&smb[s * 2048 + (wm * 32 + im * 16 + lr) * 32 + slot * 8];
#pragma unroll
        for (int in = 0; in < 4; ++in)
            bf[in] = *(const short8*)&smb[6144 + (wn * 64 + in * 16 + lr) * 32 + slot * 8];
        asm volatile("s_waitcnt lgkmcnt(0)" ::: "memory");
        __builtin_amdgcn_sched_barrier(0);
        __builtin_amdgcn_s_barrier();
        __builtin_amdgcn_sched_barrier(0);

#pragma unroll
        for (int s = 0; s < 3; ++s)
#pragma unroll
            for (int im = 0; im < 2; ++im)
#pragma unroll
                for (int in = 0; in < 4; ++in)
                    acc[im][in] = __builtin_amdgcn_mfma_f32_16x16x32_bf16(af[s][im], bf[in], acc[im][in], 0, 0, 0);
    }

    const float rs = 1.0f / sqrtf(1.0f + EPS_);
#pragma unroll
    for (int im = 0; im < 2; ++im) {
#pragma unroll
        for (int in = 0; in < 4; ++in) {
            int n_g = nb * 128 + wn * 64 + in * 16 + lr;
            int tb = n_g >> 10, hw = n_g & 1023;
#pragma unroll
            for (int r = 0; r < 4; ++r) {
                int o = mb * 64 + wm * 32 + im * 16 + quad * 4 + r;
                size_t idx = ((size_t)tb * C_ + o) * HW + hw;
                out[idx] = acc[im][in][r] * (g2[o] * rs) + b2[o] + x[idx];
            }
        }
    }
}

extern "C" void kernel_launch(void* const* d_in, const int* in_sizes, int n_in,
                              void* d_out, int out_size, void* d_ws, size_t ws_size,
                              hipStream_t stream) {
    const float* x      = (const float*)d_in[0];
    const float* Wconv  = (const float*)d_in[1];
    const float* gamma1 = (const float*)d_in[2];
    const float* beta1  = (const float*)d_in[3];
    const float* Wproj  = (const float*)d_in[4];
    const float* gamma2 = (const float*)d_in[5];
    const float* beta2  = (const float*)d_in[6];
    const float* frx    = (const float*)d_in[7];
    const float* fra    = (const float*)d_in[8];
    float* out = (float*)d_out;

    unsigned short* ws16 = (unsigned short*)d_ws;
    unsigned short* Bc  = ws16;                 // aliased by obt after k_mconv
    unsigned short* obt = ws16;
    unsigned short* Wc3 = ws16 + 6291456;
    unsigned short* Wp3 = ws16 + 9830400;
    unsigned short* xsb = ws16 + 10272768;
    unsigned short* y1s = ws16 + 16564224;
    unsigned short* y2s = ws16 + 21282816;
    unsigned long long* abits = (unsigned long long*)(ws16 + 26001408);  // 6.3 MB

    k_pre<<<6720, 256, 0, stream>>>(Wconv, Wproj, x, Wc3, Wp3, Bc, xsb);
    k_mconv<<<dim3(32, 24), 128, 0, stream>>>(Bc, Wc3, gamma1, beta1, frx, fra, y1s, y2s);
    k_attn_qk<<<dim3(16, 12, 4), 256, 0, stream>>>(xsb, y1s, (unsigned short*)abits);
    k_attn_pv<<<dim3(32, 12, 4), 128, 0, stream>>>(abits, y2s, obt);
    k_mproj<<<dim3(128, 6), 256, 0, stream>>>(obt, Wp3, gamma2, beta2, x, out);
}